// Round 7
// baseline (1968.120 us; speedup 1.0000x reference)
//
#include <hip/hip_runtime.h>

#define NB   512
#define NV   20480
#define NA   51200
#define EVV  163840
#define EAA  409600
#define EVA  61440
#define DV   1024
#define DA   128
#define HD   512
#define NOUT 128
#define NL   4

typedef __attribute__((ext_vector_type(8))) short short8;
typedef __attribute__((ext_vector_type(8))) unsigned short ushort8;
typedef __attribute__((ext_vector_type(4))) float f32x4;

__device__ inline unsigned short f2bf(float f) {
  unsigned u = __float_as_uint(f);
  return (unsigned short)((u + 0x7fffu + ((u >> 16) & 1u)) >> 16);
}
__device__ inline float bf2f(unsigned short h) {
  return __uint_as_float((unsigned)h << 16);
}

// ------- MFMA GEMM, full-N tile: C[M,512](bf16) = A[M,K](f32) @ Bt[512,K]^T -
// One block = 128 rows x all 512 cols -> A fetched exactly once per GEMM.
// 512 threads = 8 waves (2x4); each wave 64x128 (4x8 frags of 16x16), K-step 32.
__global__ __launch_bounds__(512, 2) void mfma_gemm(const float* __restrict__ A,
    const unsigned short* __restrict__ Bt, unsigned short* __restrict__ C,
    int M, int K) {
  __shared__ unsigned short As[128 * 40];   // 128 rows x 32 ks (+8 pad)
  __shared__ unsigned short Bs[512 * 40];   // 512 rows x 32 ks (+8 pad)
  const int tid = threadIdx.x;
  const int bm = blockIdx.x;
  const int l = tid & 63, wid = tid >> 6;
  const int wr = wid >> 2, wc = wid & 3;    // 2 (M) x 4 (N) waves
  const int ra = tid >> 2, ka = (tid & 3) << 3;   // A staging: 4 thr/row

  const float* ap = A + (size_t)(bm * 128 + ra) * K + ka;
  const unsigned short* btp = Bt + (size_t)tid * K;   // B staging: 1 thr/row

  f32x4 acc[4][8] = {};
  const int fr = l & 15, fq = l >> 4;
  const int arow = (wr * 64 + fr) * 40 + fq * 8;
  const int brow = (wc * 128 + fr) * 40 + fq * 8;

  for (int k0 = 0; k0 < K; k0 += 32) {
    float4 f0 = *(const float4*)(ap + k0);
    float4 f1 = *(const float4*)(ap + k0 + 4);
    short8 b0 = *(const short8*)(btp + k0);
    short8 b1 = *(const short8*)(btp + k0 + 8);
    short8 b2 = *(const short8*)(btp + k0 + 16);
    short8 b3 = *(const short8*)(btp + k0 + 24);
    short8 pa;
    pa[0] = (short)f2bf(f0.x); pa[1] = (short)f2bf(f0.y);
    pa[2] = (short)f2bf(f0.z); pa[3] = (short)f2bf(f0.w);
    pa[4] = (short)f2bf(f1.x); pa[5] = (short)f2bf(f1.y);
    pa[6] = (short)f2bf(f1.z); pa[7] = (short)f2bf(f1.w);
    __syncthreads();   // previous iteration's frag reads complete
    *(short8*)&As[ra * 40 + ka] = pa;
    *(short8*)&Bs[tid * 40 + 0]  = b0;
    *(short8*)&Bs[tid * 40 + 8]  = b1;
    *(short8*)&Bs[tid * 40 + 16] = b2;
    *(short8*)&Bs[tid * 40 + 24] = b3;
    __syncthreads();   // tile visible
    short8 a[4];
#pragma unroll
    for (int m = 0; m < 4; ++m) a[m] = *(const short8*)&As[arow + m * 16 * 40];
#pragma unroll
    for (int n = 0; n < 8; ++n) {
      short8 b = *(const short8*)&Bs[brow + n * 16 * 40];
#pragma unroll
      for (int m = 0; m < 4; ++m)
        acc[m][n] = __builtin_amdgcn_mfma_f32_16x16x32_bf16(a[m], b, acc[m][n], 0, 0, 0);
    }
  }

  // C write: row = (lane>>4)*4+reg, col = lane&15 per frag (m89/m91 layout)
#pragma unroll
  for (int m = 0; m < 4; ++m) {
#pragma unroll
    for (int n = 0; n < 8; ++n) {
      int col = wc * 128 + n * 16 + fr;
#pragma unroll
      for (int j = 0; j < 4; ++j) {
        int row = bm * 128 + wr * 64 + m * 16 + fq * 4 + j;
        C[(size_t)row * HD + col] = f2bf(acc[m][n][j]);
      }
    }
  }
}

// ------------- transpose-cast: Wt[512,K](bf16) = W[K,512](f32)^T ------------
__global__ __launch_bounds__(256) void tcast_kernel(const float* __restrict__ W,
    unsigned short* __restrict__ Wt, int K) {
  __shared__ float t[32][33];
  int n0 = blockIdx.x * 32, k0 = blockIdx.y * 32;
  int c = threadIdx.x & 31, rr = threadIdx.x >> 5;
#pragma unroll
  for (int i = 0; i < 4; ++i) {
    int row = rr + i * 8;
    t[row][c] = W[(size_t)(k0 + row) * HD + n0 + c];
  }
  __syncthreads();
#pragma unroll
  for (int i = 0; i < 4; ++i) {
    int row = rr + i * 8;
    Wt[(size_t)(n0 + row) * K + k0 + c] = f2bf(t[c][row]);
  }
}

// ---------------- small fp32 GEMM (final linear only) -----------------------
__global__ __launch_bounds__(256) void gemm64(const float* __restrict__ A,
    const float* __restrict__ B, const float* __restrict__ bias,
    float* __restrict__ C, int M, int N, int K) {
  __shared__ float As[16][68];
  __shared__ float Bs[16][68];
  const int tid = threadIdx.x;
  const int bm = blockIdx.y, bn = blockIdx.x;
  const int tx = tid & 15, ty = tid >> 4;
  const int la_m = tid >> 2, la_k = (tid & 3) << 2;
  const int lb_k = tid >> 4, lb_n = (tid & 15) << 2;
  const float* Ab = A + (size_t)bm * 64 * K;
  const float* Bb = B + bn * 64;
  float acc[4][4] = {};
  for (int k0 = 0; k0 < K; k0 += 16) {
    float4 av = *(const float4*)(Ab + (size_t)la_m * K + k0 + la_k);
    float4 bv = *(const float4*)(Bb + (size_t)(k0 + lb_k) * N + lb_n);
    __syncthreads();
    As[la_k + 0][la_m] = av.x; As[la_k + 1][la_m] = av.y;
    As[la_k + 2][la_m] = av.z; As[la_k + 3][la_m] = av.w;
    *(float4*)&Bs[lb_k][lb_n] = bv;
    __syncthreads();
#pragma unroll
    for (int k = 0; k < 16; ++k) {
      float a0 = As[k][ty * 4 + 0], a1 = As[k][ty * 4 + 1];
      float a2 = As[k][ty * 4 + 2], a3 = As[k][ty * 4 + 3];
      float b0 = Bs[k][tx * 4 + 0], b1 = Bs[k][tx * 4 + 1];
      float b2 = Bs[k][tx * 4 + 2], b3 = Bs[k][tx * 4 + 3];
      acc[0][0] += a0 * b0; acc[0][1] += a0 * b1; acc[0][2] += a0 * b2; acc[0][3] += a0 * b3;
      acc[1][0] += a1 * b0; acc[1][1] += a1 * b1; acc[1][2] += a1 * b2; acc[1][3] += a1 * b3;
      acc[2][0] += a2 * b0; acc[2][1] += a2 * b1; acc[2][2] += a2 * b2; acc[2][3] += a2 * b3;
      acc[3][0] += a3 * b0; acc[3][1] += a3 * b1; acc[3][2] += a3 * b2; acc[3][3] += a3 * b3;
    }
  }
  const int col = bn * 64 + tx * 4;
  float4 bv = make_float4(0.f, 0.f, 0.f, 0.f);
  if (bias) bv = *(const float4*)(bias + col);
#pragma unroll
  for (int i = 0; i < 4; ++i) {
    size_t row = (size_t)bm * 64 + ty * 4 + i;
    float4 v = make_float4(acc[i][0] + bv.x, acc[i][1] + bv.y,
                           acc[i][2] + bv.z, acc[i][3] + bv.w);
    *(float4*)(C + row * N + col) = v;
  }
}

// ------------- rowdot: out[n] = dot(x[n, 0:K], w[0:K]) ----------------------
__global__ __launch_bounds__(256) void rowdot_kernel(const float* __restrict__ x,
    const float* __restrict__ w, float* __restrict__ out, int N, int K) {
  int row = blockIdx.x * 4 + (threadIdx.x >> 6);
  if (row >= N) return;
  int lane = threadIdx.x & 63;
  const float* xp = x + (size_t)row * K;
  float p = 0.f;
  for (int k = lane; k < K; k += 64) p += xp[k] * w[k];
  for (int off = 32; off; off >>= 1) p += __shfl_down(p, off);
  if (lane == 0) out[row] = p;
}

// ----------------------- CSR build ------------------------------------------
__global__ __launch_bounds__(256) void deg_kernel(const int* __restrict__ dst,
    int* __restrict__ deg, int E) {
  int e = blockIdx.x * 256 + threadIdx.x;
  if (e < E) atomicAdd(deg + dst[e], 1);
}

__global__ __launch_bounds__(256) void scan1_kernel(const int* __restrict__ deg,
    int* __restrict__ bsum, int n) {
  __shared__ int sh[4];
  int b = blockIdx.x, tid = threadIdx.x;
  int lane = tid & 63, wid = tid >> 6;
  int v = 0;
#pragma unroll
  for (int j = 0; j < 4; ++j) {
    int i = b * 1024 + j * 256 + tid;
    if (i < n) v += deg[i];
  }
  for (int off = 32; off; off >>= 1) v += __shfl_down(v, off);
  if (lane == 0) sh[wid] = v;
  __syncthreads();
  if (tid == 0) bsum[b] = sh[0] + sh[1] + sh[2] + sh[3];
}

__global__ __launch_bounds__(64) void scan2_kernel(int* __restrict__ bsum, int nb,
    int* __restrict__ rp_end) {
  int tid = threadIdx.x;
  int v = (tid < nb) ? bsum[tid] : 0;
  int x = v;
#pragma unroll
  for (int off = 1; off < 64; off <<= 1) {
    int y = __shfl_up(x, off);
    if (tid >= off) x += y;
  }
  if (tid < nb) bsum[tid] = x - v;
  if (tid == 63) *rp_end = x;
}

__global__ __launch_bounds__(256) void scan3_kernel(const int* __restrict__ deg,
    const int* __restrict__ bsum, int* __restrict__ rp, int n) {
  __shared__ int wsum[4];
  int b = blockIdx.x, tid = threadIdx.x;
  int lane = tid & 63, wid = tid >> 6;
  int carry = bsum[b];
#pragma unroll
  for (int c = 0; c < 4; ++c) {
    int i = b * 1024 + c * 256 + tid;
    int v = (i < n) ? deg[i] : 0;
    int x = v;
#pragma unroll
    for (int off = 1; off < 64; off <<= 1) {
      int y = __shfl_up(x, off);
      if (lane >= off) x += y;
    }
    if (lane == 63) wsum[wid] = x;
    __syncthreads();
    int woff = 0;
    for (int k = 0; k < wid; ++k) woff += wsum[k];
    if (i < n) rp[i] = carry + woff + x - v;
    carry += wsum[0] + wsum[1] + wsum[2] + wsum[3];
    __syncthreads();
  }
}

__global__ __launch_bounds__(256) void copy_kernel(const int* __restrict__ a,
    int* __restrict__ b, int n) {
  int i = blockIdx.x * 256 + threadIdx.x;
  if (i < n) b[i] = a[i];
}

__global__ __launch_bounds__(256) void fill_kernel(const int* __restrict__ dst,
    int* __restrict__ cursor, int* __restrict__ eidx, int E) {
  int e = blockIdx.x * 256 + threadIdx.x;
  if (e >= E) return;
  int pos = atomicAdd(cursor + dst[e], 1);
  eidx[pos] = e;
}

// ------------- CSR gather: out[d] (= b1+b2) += sum_e w[e]*h[src[e]] ---------
// h is bf16 [N,512]; out/biases fp32. One wave per dst node, 8 ch/lane.
template <bool INIT>
__global__ __launch_bounds__(256) void gather_kernel(
    const unsigned short* __restrict__ h,
    const int* __restrict__ rp, const int* __restrict__ eidx,
    const int* __restrict__ esrc, const float* __restrict__ ew,
    const float* __restrict__ b1, const float* __restrict__ b2,
    float* __restrict__ out, int N) {
  int d = blockIdx.x * 4 + (threadIdx.x >> 6);
  if (d >= N) return;
  int lane = threadIdx.x & 63;
  int beg = rp[d], end = rp[d + 1];
  if (!INIT && beg == end) return;
  float* op = out + (size_t)d * HD + lane * 8;
  float4 a0, a1;
  if (INIT) {
    a0 = *(const float4*)(b1 + lane * 8);
    a1 = *(const float4*)(b1 + lane * 8 + 4);
    if (b2) {
      float4 c0 = *(const float4*)(b2 + lane * 8);
      float4 c1 = *(const float4*)(b2 + lane * 8 + 4);
      a0.x += c0.x; a0.y += c0.y; a0.z += c0.z; a0.w += c0.w;
      a1.x += c1.x; a1.y += c1.y; a1.z += c1.z; a1.w += c1.w;
    }
  } else {
    a0 = *(const float4*)(op);
    a1 = *(const float4*)(op + 4);
  }
  for (int base = beg; base < end; base += 64) {
    int cnt = end - base; if (cnt > 64) cnt = 64;
    int s = 0; float w = 0.f;
    if (lane < cnt) {
      int e = eidx[base + lane];
      s = esrc[e];
      w = ew[e];
    }
    for (int j = 0; j < cnt; ++j) {
      int sj = __shfl(s, j);
      float wj = __shfl(w, j);
      ushort8 hv = *(const ushort8*)(h + (size_t)sj * HD + lane * 8);
      a0.x += wj * bf2f(hv[0]); a0.y += wj * bf2f(hv[1]);
      a0.z += wj * bf2f(hv[2]); a0.w += wj * bf2f(hv[3]);
      a1.x += wj * bf2f(hv[4]); a1.y += wj * bf2f(hv[5]);
      a1.z += wj * bf2f(hv[6]); a1.w += wj * bf2f(hv[7]);
    }
  }
  *(float4*)(op) = a0;
  *(float4*)(op + 4) = a1;
}

// ------------------------- GAT helpers --------------------------------------
__device__ inline unsigned enc_f(float f) {
  unsigned u = __float_as_uint(f);
  return (u & 0x80000000u) ? ~u : (u | 0x80000000u);
}
__device__ inline float dec_f(unsigned k) {
  unsigned u = (k & 0x80000000u) ? (k ^ 0x80000000u) : ~k;
  return __uint_as_float(u);
}

__global__ __launch_bounds__(256) void gat_init_kernel(unsigned* __restrict__ segmax,
    float* __restrict__ segsum, int N) {
  int i = blockIdx.x * 256 + threadIdx.x;
  if (i < N) { segmax[i] = 0x007FFFFFu; segsum[i] = 0.f; }
}

__global__ __launch_bounds__(256) void gat_p1_kernel(const float* __restrict__ hs_dot,
    const float* __restrict__ hd_dot, const int* __restrict__ ei,
    unsigned* __restrict__ segmax, int E) {
  int e = blockIdx.x * 256 + threadIdx.x;
  if (e >= E) return;
  int s = ei[e], d = ei[E + e];
  float l = hs_dot[s] + hd_dot[d];
  l = (l > 0.f) ? l : 0.2f * l;
  atomicMax(segmax + d, enc_f(l));
}

__global__ __launch_bounds__(256) void gat_p2_kernel(const float* __restrict__ hs_dot,
    const float* __restrict__ hd_dot, const int* __restrict__ ei,
    const unsigned* __restrict__ segmax, float* __restrict__ segsum,
    float* __restrict__ elog, int E) {
  int e = blockIdx.x * 256 + threadIdx.x;
  if (e >= E) return;
  int s = ei[e], d = ei[E + e];
  float l = hs_dot[s] + hd_dot[d];
  l = (l > 0.f) ? l : 0.2f * l;
  float m = dec_f(segmax[d]);
  float ex = __expf(l - m);
  elog[e] = ex;
  atomicAdd(segsum + d, ex);
}

__global__ __launch_bounds__(256) void gat_p2b_kernel(const int* __restrict__ ei,
    const float* __restrict__ segsum, float* __restrict__ elog, int E) {
  int e = blockIdx.x * 256 + threadIdx.x;
  if (e >= E) return;
  int d = ei[E + e];
  elog[e] = elog[e] / segsum[d];
}

// ------------- graph norm (per graph over P nodes x 512 ch), fused relu ----
template <int P>
__global__ __launch_bounds__(512) void norm_kernel(const float* __restrict__ src,
    float* __restrict__ dst, const float* __restrict__ w, const float* __restrict__ b) {
  int g = blockIdx.x;
  int tid = threadIdx.x;
  const size_t base = (size_t)g * P * HD;
  double s = 0.0, s2 = 0.0;
  for (int n = 0; n < P; ++n) {
    float v = fmaxf(src[base + (size_t)n * HD + tid], 0.f);
    s += v; s2 += (double)v * v;
  }
  for (int off = 32; off; off >>= 1) { s += __shfl_down(s, off); s2 += __shfl_down(s2, off); }
  __shared__ double rs[8], rs2[8];
  int lane = tid & 63, wid = tid >> 6;
  if (lane == 0) { rs[wid] = s; rs2[wid] = s2; }
  __syncthreads();
  __shared__ float mean_s, rstd_s;
  if (tid == 0) {
    double S = 0, S2 = 0;
    for (int i = 0; i < 8; ++i) { S += rs[i]; S2 += rs2[i]; }
    double M = (double)P * (double)HD;
    double mean = S / M;
    double var = S2 / M - mean * mean;
    mean_s = (float)mean;
    rstd_s = (float)(1.0 / sqrt(var + 1e-5));
  }
  __syncthreads();
  float mean = mean_s, rstd = rstd_s;
  float ww = w[tid], bb = b[tid];
  for (int n = 0; n < P; ++n) {
    float v = fmaxf(src[base + (size_t)n * HD + tid], 0.f);
    dst[base + (size_t)n * HD + tid] = ww * (v - mean) * rstd + bb;
  }
}

// ------------- readout: global attention over 100 audio nodes per graph -----
__global__ __launch_bounds__(512) void readout_kernel(const float* __restrict__ xa,
    const float* __restrict__ att_w, float* __restrict__ ge) {
  int g = blockIdx.x;
  int tid = threadIdx.x;
  int lane = tid & 63, wid = tid >> 6;
  const float* xg = xa + (size_t)g * 100 * HD;
  __shared__ float gv[112];
  for (int n = wid; n < 100; n += 8) {
    float p = 0.f;
#pragma unroll
    for (int j = 0; j < 8; ++j) p += xg[(size_t)n * HD + j * 64 + lane] * att_w[j * 64 + lane];
    for (int off = 32; off; off >>= 1) p += __shfl_down(p, off);
    if (lane == 0) gv[n] = p;
  }
  __syncthreads();
  __shared__ float inv_s;
  if (tid == 0) {
    float m = -1e30f;
    for (int n = 0; n < 100; ++n) m = fmaxf(m, gv[n]);
    float ssum = 0.f;
    for (int n = 0; n < 100; ++n) { float e = __expf(gv[n] - m); gv[n] = e; ssum += e; }
    inv_s = 1.0f / fmaxf(ssum, 1e-16f);
  }
  __syncthreads();
  float inv = inv_s;
  float acc = 0.f;
  for (int n = 0; n < 100; ++n) acc += gv[n] * xg[(size_t)n * HD + tid];
  ge[(size_t)g * HD + tid] = acc * inv;
}

// ----------------------------------------------------------------------------
extern "C" void kernel_launch(void* const* d_in, const int* in_sizes, int n_in,
                              void* d_out, int out_size, void* d_ws, size_t ws_size,
                              hipStream_t stream) {
  const float* x_video = (const float*)d_in[0];
  const float* x_audio = (const float*)d_in[1];
  const float* ew_vv   = (const float*)d_in[2];
  const float* ew_aa   = (const float*)d_in[3];
  const float* W_vv0   = (const float*)d_in[4];
  const float* W_aa0   = (const float*)d_in[5];
  const float* W_src0  = (const float*)d_in[6];
  const float* W_dst0  = (const float*)d_in[7];
  const float* W_vv    = (const float*)d_in[8];
  const float* W_aa    = (const float*)d_in[9];
  const float* W_src   = (const float*)d_in[10];
  const float* W_dst   = (const float*)d_in[11];
  const float* b_vv    = (const float*)d_in[12];
  const float* b_aa    = (const float*)d_in[13];
  const float* b_gat   = (const float*)d_in[14];
  const float* a_src   = (const float*)d_in[15];
  const float* a_dst   = (const float*)d_in[16];
  const float* ln_v_w  = (const float*)d_in[17];
  const float* ln_v_b  = (const float*)d_in[18];
  const float* ln_a_w  = (const float*)d_in[19];
  const float* ln_a_b  = (const float*)d_in[20];
  const float* att_w   = (const float*)d_in[21];
  const float* lin_W   = (const float*)d_in[22];
  const float* lin_b   = (const float*)d_in[23];
  const int*   ei_vv   = (const int*)d_in[24];
  const int*   ei_aa   = (const int*)d_in[25];
  const int*   ei_va   = (const int*)d_in[26];

  // ---- workspace carve-up (4B units) ----
  const size_t WT_ELEMS = (size_t)HD * DV;
  const size_t REQ = (size_t)NV * HD + (size_t)NA * HD + (size_t)NA * HD / 2
                   + NV + NA + 1024 + 512 + NA + NA + EVA + (size_t)NB * HD
                   + (NV + 1) + EVV + (NA + 1) + EAA + (NA + 1) + EVA
                   + 3 * (WT_ELEMS / 2) + 64;
  if (ws_size < REQ * sizeof(float)) return;

  float* p = (float*)d_ws;
  float* P  = p; p += (size_t)NV * HD;
  float* Q  = p; p += (size_t)NA * HD;
  unsigned short* S = (unsigned short*)p; p += (size_t)NA * HD / 2;  // bf16 msgs
  float* hs_dot = p; p += NV;
  float* hd_dot = p; p += NA;
  float* wsa    = p; p += 1024;
  float* wda    = p; p += 512;
  unsigned* segmax = (unsigned*)p; p += NA;
  float* segsum = p; p += NA;
  float* elog   = p; p += EVA;
  float* ge     = p; p += (size_t)NB * HD;
  int* rp_vv = (int*)p; p += NV + 1;
  int* ex_vv = (int*)p; p += EVV;
  int* rp_aa = (int*)p; p += NA + 1;
  int* ex_aa = (int*)p; p += EAA;
  int* rp_va = (int*)p; p += NA + 1;
  int* ex_va = (int*)p; p += EVA;
  unsigned short* Wt_v = (unsigned short*)p; p += WT_ELEMS / 2;
  unsigned short* Wt_a = (unsigned short*)p; p += WT_ELEMS / 2;
  unsigned short* Wt_s = (unsigned short*)p; p += WT_ELEMS / 2;
  int* bsum = (int*)p; p += 64;

  int* degbuf = (int*)segmax;
  int* curbuf = (int*)segsum;

  // ---- build CSR (once; edge lists shared by all 4 layers) ----
  {
    struct { const int* dst; int* rp; int* ex; int N; int E; } g[3] = {
      { ei_vv + EVV, rp_vv, ex_vv, NV, EVV },
      { ei_aa + EAA, rp_aa, ex_aa, NA, EAA },
      { ei_va + EVA, rp_va, ex_va, NA, EVA },
    };
    for (int i = 0; i < 3; ++i) {
      int nb = (g[i].N + 1023) / 1024;
      hipMemsetAsync(degbuf, 0, (size_t)g[i].N * sizeof(int), stream);
      deg_kernel<<<(g[i].E + 255) / 256, 256, 0, stream>>>(g[i].dst, degbuf, g[i].E);
      scan1_kernel<<<nb, 256, 0, stream>>>(degbuf, bsum, g[i].N);
      scan2_kernel<<<1, 64, 0, stream>>>(bsum, nb, g[i].rp + g[i].N);
      scan3_kernel<<<nb, 256, 0, stream>>>(degbuf, bsum, g[i].rp, g[i].N);
      copy_kernel<<<(g[i].N + 255) / 256, 256, 0, stream>>>(g[i].rp, curbuf, g[i].N);
      fill_kernel<<<(g[i].E + 255) / 256, 256, 0, stream>>>(g[i].dst, curbuf, g[i].ex, g[i].E);
    }
  }

  const float* xv_cur = x_video;
  const float* xa_cur = x_audio;

  for (int i = 0; i < NL; ++i) {
    const int Kv = (i == 0) ? DV : HD;
    const int Ka = (i == 0) ? DA : HD;
    const float* Wv = (i == 0) ? W_vv0  : W_vv  + (size_t)(i - 1) * HD * HD;
    const float* Wa = (i == 0) ? W_aa0  : W_aa  + (size_t)(i - 1) * HD * HD;
    const float* Ws = (i == 0) ? W_src0 : W_src + (size_t)(i - 1) * HD * HD;
    const float* Wd = (i == 0) ? W_dst0 : W_dst + (size_t)(i - 1) * HD * HD;

    // ---- transpose-cast weights to bf16 [512 x K] ----
    tcast_kernel<<<dim3(HD / 32, Kv / 32), 256, 0, stream>>>(Wv, Wt_v, Kv);
    tcast_kernel<<<dim3(HD / 32, Ka / 32), 256, 0, stream>>>(Wa, Wt_a, Ka);
    tcast_kernel<<<dim3(HD / 32, Kv / 32), 256, 0, stream>>>(Ws, Wt_s, Kv);

    // ---- attention logit dots ((x@W)@a == x@(W@a)) ----
    rowdot_kernel<<<(Ka + 3) / 4, 256, 0, stream>>>(Wd, a_dst + i * HD, wda, Ka, HD);
    rowdot_kernel<<<NA / 4, 256, 0, stream>>>(xa_cur, wda, hd_dot, NA, Ka);
    rowdot_kernel<<<(Kv + 3) / 4, 256, 0, stream>>>(Ws, a_src + i * HD, wsa, Kv, HD);
    rowdot_kernel<<<NV / 4, 256, 0, stream>>>(xv_cur, wsa, hs_dot, NV, Kv);

    // ---- GAT softmax over incoming va edges ----
    gat_init_kernel<<<(NA + 255) / 256, 256, 0, stream>>>(segmax, segsum, NA);
    gat_p1_kernel<<<(EVA + 255) / 256, 256, 0, stream>>>(hs_dot, hd_dot, ei_va, segmax, EVA);
    gat_p2_kernel<<<(EVA + 255) / 256, 256, 0, stream>>>(hs_dot, hd_dot, ei_va, segmax, segsum, elog, EVA);
    gat_p2b_kernel<<<(EVA + 255) / 256, 256, 0, stream>>>(ei_va, segsum, elog, EVA);

    // ---- audio GCN: ha = xa@Wa -> S (bf16); gather into Q (init biases) ----
    mfma_gemm<<<NA / 128, 512, 0, stream>>>(xa_cur, Wt_a, S, NA, Ka);
    gather_kernel<true><<<NA / 4, 256, 0, stream>>>(S, rp_aa, ex_aa, ei_aa, ew_aa,
                                                    b_aa + i * HD, b_gat + i * HD, Q, NA);

    // ---- GAT value: hs = xv@Ws -> S (bf16); gather alpha*hs into Q ----
    mfma_gemm<<<NV / 128, 512, 0, stream>>>(xv_cur, Wt_s, S, NV, Kv);
    gather_kernel<false><<<NA / 4, 256, 0, stream>>>(S, rp_va, ex_va, ei_va, elog,
                                                     nullptr, nullptr, Q, NA);

    // ---- video GCN: hv = xv@Wv -> S (bf16); gather into P (init bias) ----
    mfma_gemm<<<NV / 128, 512, 0, stream>>>(xv_cur, Wt_v, S, NV, Kv);
    gather_kernel<true><<<NV / 4, 256, 0, stream>>>(S, rp_vv, ex_vv, ei_vv, ew_vv,
                                                    b_vv + i * HD, nullptr, P, NV);

    // ---- relu + graph norm (in place) ----
    norm_kernel<40><<<NB, 512, 0, stream>>>(P, P, ln_v_w + i * HD, ln_v_b + i * HD);
    norm_kernel<100><<<NB, 512, 0, stream>>>(Q, Q, ln_a_w + i * HD, ln_a_b + i * HD);

    xv_cur = P;
    xa_cur = Q;
  }

  // ---- readout + final linear (small, stays fp32) ----
  readout_kernel<<<NB, 512, 0, stream>>>(Q, att_w, ge);
  gemm64<<<dim3(NOUT / 64, NB / 64), 256, 0, stream>>>(ge, lin_W, lin_b, (float*)d_out, NB, NOUT, HD);
}

// Round 8
// 1924.976 us; speedup vs baseline: 1.0224x; 1.0224x over previous
//
#include <hip/hip_runtime.h>

#define NB   512
#define NV   20480
#define NA   51200
#define EVV  163840
#define EAA  409600
#define EVA  61440
#define DV   1024
#define DA   128
#define HD   512
#define NOUT 128
#define NL   4

typedef __attribute__((ext_vector_type(8))) short short8;
typedef __attribute__((ext_vector_type(8))) unsigned short ushort8;
typedef __attribute__((ext_vector_type(4))) float f32x4;

__device__ inline unsigned short f2bf(float f) {
  unsigned u = __float_as_uint(f);
  return (unsigned short)((u + 0x7fffu + ((u >> 16) & 1u)) >> 16);
}
__device__ inline float bf2f(unsigned short h) {
  return __uint_as_float((unsigned)h << 16);
}

// ---- MFMA GEMM 128x128 tile, XCD-swizzled; optional dual-B (shared A) ------
// C[M,512](bf16) = A[M,K](f32) @ Bt[512,K](bf16)^T   (and C1 = A @ Bt1^T)
// 256 thr = 4 waves (2x2), wave 64x64 = 4x4 frags 16x16, K-step 32.
// blockIdx decode puts the 4 bn-tiles of one bm on the SAME XCD (L2 A-reuse):
//   xcd = id&7, bn = (id>>3)&3, bm = xcd + 8*(id>>5).  Requires (M/128)%8==0.
template <bool DUAL>
__global__ __launch_bounds__(256) void mfma_gemm(const float* __restrict__ A,
    const unsigned short* __restrict__ Bt0, const unsigned short* __restrict__ Bt1,
    unsigned short* __restrict__ C0, unsigned short* __restrict__ C1, int K) {
  __shared__ unsigned short As[128 * 40];
  __shared__ unsigned short Bs0[128 * 40];
  __shared__ unsigned short Bs1[DUAL ? 128 * 40 : 1];
  const int id = blockIdx.x;
  const int xcd = id & 7;
  const int j = id >> 3;
  const int bn = j & 3;
  const int bm = xcd + ((j >> 2) << 3);
  const int tid = threadIdx.x;
  const int l = tid & 63, wid = tid >> 6;
  const int wr = wid >> 1, wc = wid & 1;
  const int r = tid >> 1;               // staging row 0..127
  const int kh = (tid & 1) << 4;        // staging k-offset 0/16

  const float* ap = A + (size_t)(bm * 128 + r) * K + kh;
  const unsigned short* bt0 = Bt0 + (size_t)(bn * 128 + r) * K + kh;
  const unsigned short* bt1 = DUAL ? Bt1 + (size_t)(bn * 128 + r) * K + kh : nullptr;

  f32x4 acc0[4][4] = {};
  f32x4 acc1[4][4] = {};
  const int fr = l & 15, fq = l >> 4;
  const int arow = (wr * 64 + fr) * 40 + fq * 8;
  const int brow = (wc * 64 + fr) * 40 + fq * 8;

  for (int k0 = 0; k0 < K; k0 += 32) {
    float4 f0 = *(const float4*)(ap + k0 + 0);
    float4 f1 = *(const float4*)(ap + k0 + 4);
    float4 f2 = *(const float4*)(ap + k0 + 8);
    float4 f3 = *(const float4*)(ap + k0 + 12);
    short8 b00 = *(const short8*)(bt0 + k0);
    short8 b01 = *(const short8*)(bt0 + k0 + 8);
    short8 b10, b11;
    if (DUAL) {
      b10 = *(const short8*)(bt1 + k0);
      b11 = *(const short8*)(bt1 + k0 + 8);
    }
    short8 p0, p1;
    p0[0] = (short)f2bf(f0.x); p0[1] = (short)f2bf(f0.y);
    p0[2] = (short)f2bf(f0.z); p0[3] = (short)f2bf(f0.w);
    p0[4] = (short)f2bf(f1.x); p0[5] = (short)f2bf(f1.y);
    p0[6] = (short)f2bf(f1.z); p0[7] = (short)f2bf(f1.w);
    p1[0] = (short)f2bf(f2.x); p1[1] = (short)f2bf(f2.y);
    p1[2] = (short)f2bf(f2.z); p1[3] = (short)f2bf(f2.w);
    p1[4] = (short)f2bf(f3.x); p1[5] = (short)f2bf(f3.y);
    p1[6] = (short)f2bf(f3.z); p1[7] = (short)f2bf(f3.w);
    __syncthreads();   // previous iteration's frag reads complete
    *(short8*)&As[r * 40 + kh] = p0;
    *(short8*)&As[r * 40 + kh + 8] = p1;
    *(short8*)&Bs0[r * 40 + kh] = b00;
    *(short8*)&Bs0[r * 40 + kh + 8] = b01;
    if (DUAL) {
      *(short8*)&Bs1[r * 40 + kh] = b10;
      *(short8*)&Bs1[r * 40 + kh + 8] = b11;
    }
    __syncthreads();   // tile visible
    short8 a[4], b[4];
#pragma unroll
    for (int m = 0; m < 4; ++m) a[m] = *(const short8*)&As[arow + m * 16 * 40];
#pragma unroll
    for (int n = 0; n < 4; ++n) b[n] = *(const short8*)&Bs0[brow + n * 16 * 40];
#pragma unroll
    for (int m = 0; m < 4; ++m)
#pragma unroll
      for (int n = 0; n < 4; ++n)
        acc0[m][n] = __builtin_amdgcn_mfma_f32_16x16x32_bf16(a[m], b[n], acc0[m][n], 0, 0, 0);
    if (DUAL) {
#pragma unroll
      for (int n = 0; n < 4; ++n) b[n] = *(const short8*)&Bs1[brow + n * 16 * 40];
#pragma unroll
      for (int m = 0; m < 4; ++m)
#pragma unroll
        for (int n = 0; n < 4; ++n)
          acc1[m][n] = __builtin_amdgcn_mfma_f32_16x16x32_bf16(a[m], b[n], acc1[m][n], 0, 0, 0);
    }
  }

  // C write: row = (lane>>4)*4+reg, col = lane&15 per frag (m89/m91 layout)
#pragma unroll
  for (int m = 0; m < 4; ++m) {
#pragma unroll
    for (int n = 0; n < 4; ++n) {
      int col = bn * 128 + wc * 64 + n * 16 + fr;
#pragma unroll
      for (int j2 = 0; j2 < 4; ++j2) {
        int row = bm * 128 + wr * 64 + m * 16 + fq * 4 + j2;
        C0[(size_t)row * HD + col] = f2bf(acc0[m][n][j2]);
        if (DUAL) C1[(size_t)row * HD + col] = f2bf(acc1[m][n][j2]);
      }
    }
  }
}

// ------------- transpose-cast: Wt[512,K](bf16) = W[K,512](f32)^T ------------
__global__ __launch_bounds__(256) void tcast_kernel(const float* __restrict__ W,
    unsigned short* __restrict__ Wt, int K) {
  __shared__ float t[32][33];
  int n0 = blockIdx.x * 32, k0 = blockIdx.y * 32;
  int c = threadIdx.x & 31, rr = threadIdx.x >> 5;
#pragma unroll
  for (int i = 0; i < 4; ++i) {
    int row = rr + i * 8;
    t[row][c] = W[(size_t)(k0 + row) * HD + n0 + c];
  }
  __syncthreads();
#pragma unroll
  for (int i = 0; i < 4; ++i) {
    int row = rr + i * 8;
    Wt[(size_t)(n0 + row) * K + k0 + c] = f2bf(t[c][row]);
  }
}

// ---------------- small fp32 GEMM (final linear only) -----------------------
__global__ __launch_bounds__(256) void gemm64(const float* __restrict__ A,
    const float* __restrict__ B, const float* __restrict__ bias,
    float* __restrict__ C, int M, int N, int K) {
  __shared__ float As[16][68];
  __shared__ float Bs[16][68];
  const int tid = threadIdx.x;
  const int bm = blockIdx.y, bn = blockIdx.x;
  const int tx = tid & 15, ty = tid >> 4;
  const int la_m = tid >> 2, la_k = (tid & 3) << 2;
  const int lb_k = tid >> 4, lb_n = (tid & 15) << 2;
  const float* Ab = A + (size_t)bm * 64 * K;
  const float* Bb = B + bn * 64;
  float acc[4][4] = {};
  for (int k0 = 0; k0 < K; k0 += 16) {
    float4 av = *(const float4*)(Ab + (size_t)la_m * K + k0 + la_k);
    float4 bv = *(const float4*)(Bb + (size_t)(k0 + lb_k) * N + lb_n);
    __syncthreads();
    As[la_k + 0][la_m] = av.x; As[la_k + 1][la_m] = av.y;
    As[la_k + 2][la_m] = av.z; As[la_k + 3][la_m] = av.w;
    *(float4*)&Bs[lb_k][lb_n] = bv;
    __syncthreads();
#pragma unroll
    for (int k = 0; k < 16; ++k) {
      float a0 = As[k][ty * 4 + 0], a1 = As[k][ty * 4 + 1];
      float a2 = As[k][ty * 4 + 2], a3 = As[k][ty * 4 + 3];
      float b0 = Bs[k][tx * 4 + 0], b1 = Bs[k][tx * 4 + 1];
      float b2 = Bs[k][tx * 4 + 2], b3 = Bs[k][tx * 4 + 3];
      acc[0][0] += a0 * b0; acc[0][1] += a0 * b1; acc[0][2] += a0 * b2; acc[0][3] += a0 * b3;
      acc[1][0] += a1 * b0; acc[1][1] += a1 * b1; acc[1][2] += a1 * b2; acc[1][3] += a1 * b3;
      acc[2][0] += a2 * b0; acc[2][1] += a2 * b1; acc[2][2] += a2 * b2; acc[2][3] += a2 * b3;
      acc[3][0] += a3 * b0; acc[3][1] += a3 * b1; acc[3][2] += a3 * b2; acc[3][3] += a3 * b3;
    }
  }
  const int col = bn * 64 + tx * 4;
  float4 bv = make_float4(0.f, 0.f, 0.f, 0.f);
  if (bias) bv = *(const float4*)(bias + col);
#pragma unroll
  for (int i = 0; i < 4; ++i) {
    size_t row = (size_t)bm * 64 + ty * 4 + i;
    float4 v = make_float4(acc[i][0] + bv.x, acc[i][1] + bv.y,
                           acc[i][2] + bv.z, acc[i][3] + bv.w);
    *(float4*)(C + row * N + col) = v;
  }
}

// ------------- rowdot: out[n] = dot(x[n, 0:K], w[0:K]) ----------------------
__global__ __launch_bounds__(256) void rowdot_kernel(const float* __restrict__ x,
    const float* __restrict__ w, float* __restrict__ out, int N, int K) {
  int row = blockIdx.x * 4 + (threadIdx.x >> 6);
  if (row >= N) return;
  int lane = threadIdx.x & 63;
  const float* xp = x + (size_t)row * K;
  float p = 0.f;
  for (int k = lane; k < K; k += 64) p += xp[k] * w[k];
  for (int off = 32; off; off >>= 1) p += __shfl_down(p, off);
  if (lane == 0) out[row] = p;
}

// ----------------------- CSR build ------------------------------------------
__global__ __launch_bounds__(256) void deg_kernel(const int* __restrict__ dst,
    int* __restrict__ deg, int E) {
  int e = blockIdx.x * 256 + threadIdx.x;
  if (e < E) atomicAdd(deg + dst[e], 1);
}

__global__ __launch_bounds__(256) void scan1_kernel(const int* __restrict__ deg,
    int* __restrict__ bsum, int n) {
  __shared__ int sh[4];
  int b = blockIdx.x, tid = threadIdx.x;
  int lane = tid & 63, wid = tid >> 6;
  int v = 0;
#pragma unroll
  for (int j = 0; j < 4; ++j) {
    int i = b * 1024 + j * 256 + tid;
    if (i < n) v += deg[i];
  }
  for (int off = 32; off; off >>= 1) v += __shfl_down(v, off);
  if (lane == 0) sh[wid] = v;
  __syncthreads();
  if (tid == 0) bsum[b] = sh[0] + sh[1] + sh[2] + sh[3];
}

__global__ __launch_bounds__(64) void scan2_kernel(int* __restrict__ bsum, int nb,
    int* __restrict__ rp_end) {
  int tid = threadIdx.x;
  int v = (tid < nb) ? bsum[tid] : 0;
  int x = v;
#pragma unroll
  for (int off = 1; off < 64; off <<= 1) {
    int y = __shfl_up(x, off);
    if (tid >= off) x += y;
  }
  if (tid < nb) bsum[tid] = x - v;
  if (tid == 63) *rp_end = x;
}

__global__ __launch_bounds__(256) void scan3_kernel(const int* __restrict__ deg,
    const int* __restrict__ bsum, int* __restrict__ rp, int n) {
  __shared__ int wsum[4];
  int b = blockIdx.x, tid = threadIdx.x;
  int lane = tid & 63, wid = tid >> 6;
  int carry = bsum[b];
#pragma unroll
  for (int c = 0; c < 4; ++c) {
    int i = b * 1024 + c * 256 + tid;
    int v = (i < n) ? deg[i] : 0;
    int x = v;
#pragma unroll
    for (int off = 1; off < 64; off <<= 1) {
      int y = __shfl_up(x, off);
      if (lane >= off) x += y;
    }
    if (lane == 63) wsum[wid] = x;
    __syncthreads();
    int woff = 0;
    for (int k = 0; k < wid; ++k) woff += wsum[k];
    if (i < n) rp[i] = carry + woff + x - v;
    carry += wsum[0] + wsum[1] + wsum[2] + wsum[3];
    __syncthreads();
  }
}

__global__ __launch_bounds__(256) void copy_kernel(const int* __restrict__ a,
    int* __restrict__ b, int n) {
  int i = blockIdx.x * 256 + threadIdx.x;
  if (i < n) b[i] = a[i];
}

__global__ __launch_bounds__(256) void fill_kernel(const int* __restrict__ dst,
    int* __restrict__ cursor, int* __restrict__ eidx, int E) {
  int e = blockIdx.x * 256 + threadIdx.x;
  if (e >= E) return;
  int pos = atomicAdd(cursor + dst[e], 1);
  eidx[pos] = e;
}

// ------------- CSR gather: out[d] (= b1+b2) += sum_e w[e]*h[src[e]] ---------
// h is bf16 [N,512]; out/biases fp32. One wave per dst node, 8 ch/lane.
template <bool INIT>
__global__ __launch_bounds__(256) void gather_kernel(
    const unsigned short* __restrict__ h,
    const int* __restrict__ rp, const int* __restrict__ eidx,
    const int* __restrict__ esrc, const float* __restrict__ ew,
    const float* __restrict__ b1, const float* __restrict__ b2,
    float* __restrict__ out, int N) {
  int d = blockIdx.x * 4 + (threadIdx.x >> 6);
  if (d >= N) return;
  int lane = threadIdx.x & 63;
  int beg = rp[d], end = rp[d + 1];
  if (!INIT && beg == end) return;
  float* op = out + (size_t)d * HD + lane * 8;
  float4 a0, a1;
  if (INIT) {
    a0 = *(const float4*)(b1 + lane * 8);
    a1 = *(const float4*)(b1 + lane * 8 + 4);
    if (b2) {
      float4 c0 = *(const float4*)(b2 + lane * 8);
      float4 c1 = *(const float4*)(b2 + lane * 8 + 4);
      a0.x += c0.x; a0.y += c0.y; a0.z += c0.z; a0.w += c0.w;
      a1.x += c1.x; a1.y += c1.y; a1.z += c1.z; a1.w += c1.w;
    }
  } else {
    a0 = *(const float4*)(op);
    a1 = *(const float4*)(op + 4);
  }
  for (int base = beg; base < end; base += 64) {
    int cnt = end - base; if (cnt > 64) cnt = 64;
    int s = 0; float w = 0.f;
    if (lane < cnt) {
      int e = eidx[base + lane];
      s = esrc[e];
      w = ew[e];
    }
    for (int j = 0; j < cnt; ++j) {
      int sj = __shfl(s, j);
      float wj = __shfl(w, j);
      ushort8 hv = *(const ushort8*)(h + (size_t)sj * HD + lane * 8);
      a0.x += wj * bf2f(hv[0]); a0.y += wj * bf2f(hv[1]);
      a0.z += wj * bf2f(hv[2]); a0.w += wj * bf2f(hv[3]);
      a1.x += wj * bf2f(hv[4]); a1.y += wj * bf2f(hv[5]);
      a1.z += wj * bf2f(hv[6]); a1.w += wj * bf2f(hv[7]);
    }
  }
  *(float4*)(op) = a0;
  *(float4*)(op + 4) = a1;
}

// ------------------------- GAT helpers --------------------------------------
__device__ inline unsigned enc_f(float f) {
  unsigned u = __float_as_uint(f);
  return (u & 0x80000000u) ? ~u : (u | 0x80000000u);
}
__device__ inline float dec_f(unsigned k) {
  unsigned u = (k & 0x80000000u) ? (k ^ 0x80000000u) : ~k;
  return __uint_as_float(u);
}

__global__ __launch_bounds__(256) void gat_init_kernel(unsigned* __restrict__ segmax,
    float* __restrict__ segsum, int N) {
  int i = blockIdx.x * 256 + threadIdx.x;
  if (i < N) { segmax[i] = 0x007FFFFFu; segsum[i] = 0.f; }
}

__global__ __launch_bounds__(256) void gat_p1_kernel(const float* __restrict__ hs_dot,
    const float* __restrict__ hd_dot, const int* __restrict__ ei,
    unsigned* __restrict__ segmax, int E) {
  int e = blockIdx.x * 256 + threadIdx.x;
  if (e >= E) return;
  int s = ei[e], d = ei[E + e];
  float l = hs_dot[s] + hd_dot[d];
  l = (l > 0.f) ? l : 0.2f * l;
  atomicMax(segmax + d, enc_f(l));
}

__global__ __launch_bounds__(256) void gat_p2_kernel(const float* __restrict__ hs_dot,
    const float* __restrict__ hd_dot, const int* __restrict__ ei,
    const unsigned* __restrict__ segmax, float* __restrict__ segsum,
    float* __restrict__ elog, int E) {
  int e = blockIdx.x * 256 + threadIdx.x;
  if (e >= E) return;
  int s = ei[e], d = ei[E + e];
  float l = hs_dot[s] + hd_dot[d];
  l = (l > 0.f) ? l : 0.2f * l;
  float m = dec_f(segmax[d]);
  float ex = __expf(l - m);
  elog[e] = ex;
  atomicAdd(segsum + d, ex);
}

__global__ __launch_bounds__(256) void gat_p2b_kernel(const int* __restrict__ ei,
    const float* __restrict__ segsum, float* __restrict__ elog, int E) {
  int e = blockIdx.x * 256 + threadIdx.x;
  if (e >= E) return;
  int d = ei[E + e];
  elog[e] = elog[e] / segsum[d];
}

// ------------- graph norm (per graph over P nodes x 512 ch), fused relu ----
template <int P>
__global__ __launch_bounds__(512) void norm_kernel(const float* __restrict__ src,
    float* __restrict__ dst, const float* __restrict__ w, const float* __restrict__ b) {
  int g = blockIdx.x;
  int tid = threadIdx.x;
  const size_t base = (size_t)g * P * HD;
  double s = 0.0, s2 = 0.0;
  for (int n = 0; n < P; ++n) {
    float v = fmaxf(src[base + (size_t)n * HD + tid], 0.f);
    s += v; s2 += (double)v * v;
  }
  for (int off = 32; off; off >>= 1) { s += __shfl_down(s, off); s2 += __shfl_down(s2, off); }
  __shared__ double rs[8], rs2[8];
  int lane = tid & 63, wid = tid >> 6;
  if (lane == 0) { rs[wid] = s; rs2[wid] = s2; }
  __syncthreads();
  __shared__ float mean_s, rstd_s;
  if (tid == 0) {
    double S = 0, S2 = 0;
    for (int i = 0; i < 8; ++i) { S += rs[i]; S2 += rs2[i]; }
    double M = (double)P * (double)HD;
    double mean = S / M;
    double var = S2 / M - mean * mean;
    mean_s = (float)mean;
    rstd_s = (float)(1.0 / sqrt(var + 1e-5));
  }
  __syncthreads();
  float mean = mean_s, rstd = rstd_s;
  float ww = w[tid], bb = b[tid];
  for (int n = 0; n < P; ++n) {
    float v = fmaxf(src[base + (size_t)n * HD + tid], 0.f);
    dst[base + (size_t)n * HD + tid] = ww * (v - mean) * rstd + bb;
  }
}

// ------------- readout: global attention over 100 audio nodes per graph -----
__global__ __launch_bounds__(512) void readout_kernel(const float* __restrict__ xa,
    const float* __restrict__ att_w, float* __restrict__ ge) {
  int g = blockIdx.x;
  int tid = threadIdx.x;
  int lane = tid & 63, wid = tid >> 6;
  const float* xg = xa + (size_t)g * 100 * HD;
  __shared__ float gv[112];
  for (int n = wid; n < 100; n += 8) {
    float p = 0.f;
#pragma unroll
    for (int j = 0; j < 8; ++j) p += xg[(size_t)n * HD + j * 64 + lane] * att_w[j * 64 + lane];
    for (int off = 32; off; off >>= 1) p += __shfl_down(p, off);
    if (lane == 0) gv[n] = p;
  }
  __syncthreads();
  __shared__ float inv_s;
  if (tid == 0) {
    float m = -1e30f;
    for (int n = 0; n < 100; ++n) m = fmaxf(m, gv[n]);
    float ssum = 0.f;
    for (int n = 0; n < 100; ++n) { float e = __expf(gv[n] - m); gv[n] = e; ssum += e; }
    inv_s = 1.0f / fmaxf(ssum, 1e-16f);
  }
  __syncthreads();
  float inv = inv_s;
  float acc = 0.f;
  for (int n = 0; n < 100; ++n) acc += gv[n] * xg[(size_t)n * HD + tid];
  ge[(size_t)g * HD + tid] = acc * inv;
}

// ----------------------------------------------------------------------------
extern "C" void kernel_launch(void* const* d_in, const int* in_sizes, int n_in,
                              void* d_out, int out_size, void* d_ws, size_t ws_size,
                              hipStream_t stream) {
  const float* x_video = (const float*)d_in[0];
  const float* x_audio = (const float*)d_in[1];
  const float* ew_vv   = (const float*)d_in[2];
  const float* ew_aa   = (const float*)d_in[3];
  const float* W_vv0   = (const float*)d_in[4];
  const float* W_aa0   = (const float*)d_in[5];
  const float* W_src0  = (const float*)d_in[6];
  const float* W_dst0  = (const float*)d_in[7];
  const float* W_vv    = (const float*)d_in[8];
  const float* W_aa    = (const float*)d_in[9];
  const float* W_src   = (const float*)d_in[10];
  const float* W_dst   = (const float*)d_in[11];
  const float* b_vv    = (const float*)d_in[12];
  const float* b_aa    = (const float*)d_in[13];
  const float* b_gat   = (const float*)d_in[14];
  const float* a_src   = (const float*)d_in[15];
  const float* a_dst   = (const float*)d_in[16];
  const float* ln_v_w  = (const float*)d_in[17];
  const float* ln_v_b  = (const float*)d_in[18];
  const float* ln_a_w  = (const float*)d_in[19];
  const float* ln_a_b  = (const float*)d_in[20];
  const float* att_w   = (const float*)d_in[21];
  const float* lin_W   = (const float*)d_in[22];
  const float* lin_b   = (const float*)d_in[23];
  const int*   ei_vv   = (const int*)d_in[24];
  const int*   ei_aa   = (const int*)d_in[25];
  const int*   ei_va   = (const int*)d_in[26];

  // ---- workspace carve-up (4B units); total ~249 MB (round-2 proved >=253) --
  const size_t WT_ELEMS = (size_t)HD * DV;
  const size_t REQ = (size_t)NV * HD + (size_t)NA * HD
                   + (size_t)NA * HD / 2 + (size_t)NV * HD   // S_a + S_s + S_v
                   + NV + NA + 1024 + 512 + NA + NA + EVA + (size_t)NB * HD
                   + (NV + 1) + EVV + (NA + 1) + EAA + (NA + 1) + EVA
                   + 3 * (WT_ELEMS / 2) + 64;
  if (ws_size < REQ * sizeof(float)) return;

  float* p = (float*)d_ws;
  float* P  = p; p += (size_t)NV * HD;
  float* Q  = p; p += (size_t)NA * HD;
  unsigned short* S_a = (unsigned short*)p; p += (size_t)NA * HD / 2;  // ha bf16
  unsigned short* S_s = (unsigned short*)p; p += (size_t)NV * HD / 2;  // hs bf16
  unsigned short* S_v = (unsigned short*)p; p += (size_t)NV * HD / 2;  // hv bf16
  float* hs_dot = p; p += NV;
  float* hd_dot = p; p += NA;
  float* wsa    = p; p += 1024;
  float* wda    = p; p += 512;
  unsigned* segmax = (unsigned*)p; p += NA;
  float* segsum = p; p += NA;
  float* elog   = p; p += EVA;
  float* ge     = p; p += (size_t)NB * HD;
  int* rp_vv = (int*)p; p += NV + 1;
  int* ex_vv = (int*)p; p += EVV;
  int* rp_aa = (int*)p; p += NA + 1;
  int* ex_aa = (int*)p; p += EAA;
  int* rp_va = (int*)p; p += NA + 1;
  int* ex_va = (int*)p; p += EVA;
  unsigned short* Wt_v = (unsigned short*)p; p += WT_ELEMS / 2;
  unsigned short* Wt_a = (unsigned short*)p; p += WT_ELEMS / 2;
  unsigned short* Wt_s = (unsigned short*)p; p += WT_ELEMS / 2;
  int* bsum = (int*)p; p += 64;

  int* degbuf = (int*)segmax;
  int* curbuf = (int*)segsum;

  // ---- build CSR (once; edge lists shared by all 4 layers) ----
  {
    struct { const int* dst; int* rp; int* ex; int N; int E; } g[3] = {
      { ei_vv + EVV, rp_vv, ex_vv, NV, EVV },
      { ei_aa + EAA, rp_aa, ex_aa, NA, EAA },
      { ei_va + EVA, rp_va, ex_va, NA, EVA },
    };
    for (int i = 0; i < 3; ++i) {
      int nb = (g[i].N + 1023) / 1024;
      hipMemsetAsync(degbuf, 0, (size_t)g[i].N * sizeof(int), stream);
      deg_kernel<<<(g[i].E + 255) / 256, 256, 0, stream>>>(g[i].dst, degbuf, g[i].E);
      scan1_kernel<<<nb, 256, 0, stream>>>(degbuf, bsum, g[i].N);
      scan2_kernel<<<1, 64, 0, stream>>>(bsum, nb, g[i].rp + g[i].N);
      scan3_kernel<<<nb, 256, 0, stream>>>(degbuf, bsum, g[i].rp, g[i].N);
      copy_kernel<<<(g[i].N + 255) / 256, 256, 0, stream>>>(g[i].rp, curbuf, g[i].N);
      fill_kernel<<<(g[i].E + 255) / 256, 256, 0, stream>>>(g[i].dst, curbuf, g[i].ex, g[i].E);
    }
  }

  const float* xv_cur = x_video;
  const float* xa_cur = x_audio;

  for (int i = 0; i < NL; ++i) {
    const int Kv = (i == 0) ? DV : HD;
    const int Ka = (i == 0) ? DA : HD;
    const float* Wv = (i == 0) ? W_vv0  : W_vv  + (size_t)(i - 1) * HD * HD;
    const float* Wa = (i == 0) ? W_aa0  : W_aa  + (size_t)(i - 1) * HD * HD;
    const float* Ws = (i == 0) ? W_src0 : W_src + (size_t)(i - 1) * HD * HD;
    const float* Wd = (i == 0) ? W_dst0 : W_dst + (size_t)(i - 1) * HD * HD;

    // ---- transpose-cast weights to bf16 [512 x K] ----
    tcast_kernel<<<dim3(HD / 32, Kv / 32), 256, 0, stream>>>(Wv, Wt_v, Kv);
    tcast_kernel<<<dim3(HD / 32, Ka / 32), 256, 0, stream>>>(Wa, Wt_a, Ka);
    tcast_kernel<<<dim3(HD / 32, Kv / 32), 256, 0, stream>>>(Ws, Wt_s, Kv);

    // ---- attention logit dots ((x@W)@a == x@(W@a)) ----
    rowdot_kernel<<<(Ka + 3) / 4, 256, 0, stream>>>(Wd, a_dst + i * HD, wda, Ka, HD);
    rowdot_kernel<<<NA / 4, 256, 0, stream>>>(xa_cur, wda, hd_dot, NA, Ka);
    rowdot_kernel<<<(Kv + 3) / 4, 256, 0, stream>>>(Ws, a_src + i * HD, wsa, Kv, HD);
    rowdot_kernel<<<NV / 4, 256, 0, stream>>>(xv_cur, wsa, hs_dot, NV, Kv);

    // ---- GAT softmax over incoming va edges ----
    gat_init_kernel<<<(NA + 255) / 256, 256, 0, stream>>>(segmax, segsum, NA);
    gat_p1_kernel<<<(EVA + 255) / 256, 256, 0, stream>>>(hs_dot, hd_dot, ei_va, segmax, EVA);
    gat_p2_kernel<<<(EVA + 255) / 256, 256, 0, stream>>>(hs_dot, hd_dot, ei_va, segmax, segsum, elog, EVA);
    gat_p2b_kernel<<<(EVA + 255) / 256, 256, 0, stream>>>(ei_va, segsum, elog, EVA);

    // ---- GEMMs: dual video (hs,hv share A) + audio ----
    mfma_gemm<true><<<(NV / 128) * 4, 256, 0, stream>>>(xv_cur, Wt_s, Wt_v, S_s, S_v, Kv);
    mfma_gemm<false><<<(NA / 128) * 4, 256, 0, stream>>>(xa_cur, Wt_a, nullptr, S_a, nullptr, Ka);

    // ---- gathers: aa (init biases) -> va accumulate -> vv (init bias) ----
    gather_kernel<true><<<NA / 4, 256, 0, stream>>>(S_a, rp_aa, ex_aa, ei_aa, ew_aa,
                                                    b_aa + i * HD, b_gat + i * HD, Q, NA);
    gather_kernel<false><<<NA / 4, 256, 0, stream>>>(S_s, rp_va, ex_va, ei_va, elog,
                                                     nullptr, nullptr, Q, NA);
    gather_kernel<true><<<NV / 4, 256, 0, stream>>>(S_v, rp_vv, ex_vv, ei_vv, ew_vv,
                                                    b_vv + i * HD, nullptr, P, NV);

    // ---- relu + graph norm (in place) ----
    norm_kernel<40><<<NB, 512, 0, stream>>>(P, P, ln_v_w + i * HD, ln_v_b + i * HD);
    norm_kernel<100><<<NB, 512, 0, stream>>>(Q, Q, ln_a_w + i * HD, ln_a_b + i * HD);

    xv_cur = P;
    xa_cur = Q;
  }

  // ---- readout + final linear (small, stays fp32) ----
  readout_kernel<<<NB, 512, 0, stream>>>(Q, att_w, ge);
  gemm64<<<dim3(NOUT / 64, NB / 64), 256, 0, stream>>>(ge, lin_W, lin_b, (float*)d_out, NB, NOUT, HD);
}

// Round 9
// 1584.189 us; speedup vs baseline: 1.2424x; 1.2151x over previous
//
#include <hip/hip_runtime.h>

#define NB   512
#define NV   20480
#define NA   51200
#define EVV  163840
#define EAA  409600
#define EVA  61440
#define DV   1024
#define DA   128
#define HD   512
#define NOUT 128
#define NL   4

#define VTILES 160           // NV/128
#define ATILES 400           // NA/128
#define GSEC0  (VTILES * 4)  // 640  (hs)
#define GSEC1  (GSEC0 * 2)   // 1280 (hv)
#define GTOT   (GSEC1 + ATILES * 4)  // 2880

typedef __attribute__((ext_vector_type(8))) short short8;
typedef __attribute__((ext_vector_type(8))) unsigned short ushort8;
typedef __attribute__((ext_vector_type(4))) float f32x4;

__device__ inline unsigned short f2bf(float f) {
  unsigned u = __float_as_uint(f);
  return (unsigned short)((u + 0x7fffu + ((u >> 16) & 1u)) >> 16);
}
__device__ inline float bf2f(unsigned short h) {
  return __uint_as_float((unsigned)h << 16);
}

// ---- merged MFMA GEMM: three single-B 128x128-tile GEMMs in ONE grid -------
// sections: [0,640) hs=xv@Ws, [640,1280) hv=xv@Wv, [1280,2880) ha=xa@Wa.
// 256 thr = 4 waves (2x2), wave 64x64 = 4x4 frags 16x16, K-step 32.
// Per-section XCD swizzle: xcd=lid&7, bn=(lid>>3)&3, bm=xcd+8*(lid>>5);
// section sizes %8==0 so the decode stays XCD-aligned. A fp32 -> bf16 in staging.
__global__ __launch_bounds__(256) void mfma_gemm3(const float* __restrict__ xv,
    const float* __restrict__ xa,
    const unsigned short* __restrict__ Wt_s, const unsigned short* __restrict__ Wt_v,
    const unsigned short* __restrict__ Wt_a,
    unsigned short* __restrict__ S_s, unsigned short* __restrict__ S_v,
    unsigned short* __restrict__ S_a, int Kv, int Ka) {
  __shared__ unsigned short As[128 * 40];
  __shared__ unsigned short Bs[128 * 40];
  const int id = blockIdx.x;
  const float* A; const unsigned short* Bt; unsigned short* C; int K; int lid;
  if (id < GSEC0)      { A = xv; Bt = Wt_s; C = S_s; K = Kv; lid = id; }
  else if (id < GSEC1) { A = xv; Bt = Wt_v; C = S_v; K = Kv; lid = id - GSEC0; }
  else                 { A = xa; Bt = Wt_a; C = S_a; K = Ka; lid = id - GSEC1; }
  const int xcd = lid & 7;
  const int j = lid >> 3;
  const int bn = j & 3;
  const int bm = xcd + ((j >> 2) << 3);
  const int tid = threadIdx.x;
  const int l = tid & 63, wid = tid >> 6;
  const int wr = wid >> 1, wc = wid & 1;
  const int r = tid >> 1;               // staging row 0..127
  const int kh = (tid & 1) << 4;        // staging k-offset 0/16

  const float* ap = A + (size_t)(bm * 128 + r) * K + kh;
  const unsigned short* btp = Bt + (size_t)(bn * 128 + r) * K + kh;

  f32x4 acc[4][4] = {};
  const int fr = l & 15, fq = l >> 4;
  const int arow = (wr * 64 + fr) * 40 + fq * 8;
  const int brow = (wc * 64 + fr) * 40 + fq * 8;

  for (int k0 = 0; k0 < K; k0 += 32) {
    float4 f0 = *(const float4*)(ap + k0 + 0);
    float4 f1 = *(const float4*)(ap + k0 + 4);
    float4 f2 = *(const float4*)(ap + k0 + 8);
    float4 f3 = *(const float4*)(ap + k0 + 12);
    short8 bv0 = *(const short8*)(btp + k0);
    short8 bv1 = *(const short8*)(btp + k0 + 8);
    short8 p0, p1;
    p0[0] = (short)f2bf(f0.x); p0[1] = (short)f2bf(f0.y);
    p0[2] = (short)f2bf(f0.z); p0[3] = (short)f2bf(f0.w);
    p0[4] = (short)f2bf(f1.x); p0[5] = (short)f2bf(f1.y);
    p0[6] = (short)f2bf(f1.z); p0[7] = (short)f2bf(f1.w);
    p1[0] = (short)f2bf(f2.x); p1[1] = (short)f2bf(f2.y);
    p1[2] = (short)f2bf(f2.z); p1[3] = (short)f2bf(f2.w);
    p1[4] = (short)f2bf(f3.x); p1[5] = (short)f2bf(f3.y);
    p1[6] = (short)f2bf(f3.z); p1[7] = (short)f2bf(f3.w);
    __syncthreads();   // previous iteration's frag reads complete
    *(short8*)&As[r * 40 + kh] = p0;
    *(short8*)&As[r * 40 + kh + 8] = p1;
    *(short8*)&Bs[r * 40 + kh] = bv0;
    *(short8*)&Bs[r * 40 + kh + 8] = bv1;
    __syncthreads();   // tile visible
    short8 a[4], b[4];
#pragma unroll
    for (int m = 0; m < 4; ++m) a[m] = *(const short8*)&As[arow + m * 16 * 40];
#pragma unroll
    for (int n = 0; n < 4; ++n) b[n] = *(const short8*)&Bs[brow + n * 16 * 40];
#pragma unroll
    for (int m = 0; m < 4; ++m)
#pragma unroll
      for (int n = 0; n < 4; ++n)
        acc[m][n] = __builtin_amdgcn_mfma_f32_16x16x32_bf16(a[m], b[n], acc[m][n], 0, 0, 0);
  }

  // C write: row = (lane>>4)*4+reg, col = lane&15 per frag (m89/m91 layout)
#pragma unroll
  for (int m = 0; m < 4; ++m) {
#pragma unroll
    for (int n = 0; n < 4; ++n) {
      int col = bn * 128 + wc * 64 + n * 16 + fr;
#pragma unroll
      for (int j2 = 0; j2 < 4; ++j2) {
        int row = bm * 128 + wr * 64 + m * 16 + fq * 4 + j2;
        C[(size_t)row * HD + col] = f2bf(acc[m][n][j2]);
      }
    }
  }
}

// ------------- transpose-cast: Wt[512,K](bf16) = W[K,512](f32)^T ------------
__global__ __launch_bounds__(256) void tcast_kernel(const float* __restrict__ W,
    unsigned short* __restrict__ Wt, int K) {
  __shared__ float t[32][33];
  int n0 = blockIdx.x * 32, k0 = blockIdx.y * 32;
  int c = threadIdx.x & 31, rr = threadIdx.x >> 5;
#pragma unroll
  for (int i = 0; i < 4; ++i) {
    int row = rr + i * 8;
    t[row][c] = W[(size_t)(k0 + row) * HD + n0 + c];
  }
  __syncthreads();
#pragma unroll
  for (int i = 0; i < 4; ++i) {
    int row = rr + i * 8;
    Wt[(size_t)(n0 + row) * K + k0 + c] = f2bf(t[c][row]);
  }
}

// ---------------- small fp32 GEMM (final linear only) -----------------------
__global__ __launch_bounds__(256) void gemm64(const float* __restrict__ A,
    const float* __restrict__ B, const float* __restrict__ bias,
    float* __restrict__ C, int M, int N, int K) {
  __shared__ float As[16][68];
  __shared__ float Bs[16][68];
  const int tid = threadIdx.x;
  const int bm = blockIdx.y, bn = blockIdx.x;
  const int tx = tid & 15, ty = tid >> 4;
  const int la_m = tid >> 2, la_k = (tid & 3) << 2;
  const int lb_k = tid >> 4, lb_n = (tid & 15) << 2;
  const float* Ab = A + (size_t)bm * 64 * K;
  const float* Bb = B + bn * 64;
  float acc[4][4] = {};
  for (int k0 = 0; k0 < K; k0 += 16) {
    float4 av = *(const float4*)(Ab + (size_t)la_m * K + k0 + la_k);
    float4 bv = *(const float4*)(Bb + (size_t)(k0 + lb_k) * N + lb_n);
    __syncthreads();
    As[la_k + 0][la_m] = av.x; As[la_k + 1][la_m] = av.y;
    As[la_k + 2][la_m] = av.z; As[la_k + 3][la_m] = av.w;
    *(float4*)&Bs[lb_k][lb_n] = bv;
    __syncthreads();
#pragma unroll
    for (int k = 0; k < 16; ++k) {
      float a0 = As[k][ty * 4 + 0], a1 = As[k][ty * 4 + 1];
      float a2 = As[k][ty * 4 + 2], a3 = As[k][ty * 4 + 3];
      float b0 = Bs[k][tx * 4 + 0], b1 = Bs[k][tx * 4 + 1];
      float b2 = Bs[k][tx * 4 + 2], b3 = Bs[k][tx * 4 + 3];
      acc[0][0] += a0 * b0; acc[0][1] += a0 * b1; acc[0][2] += a0 * b2; acc[0][3] += a0 * b3;
      acc[1][0] += a1 * b0; acc[1][1] += a1 * b1; acc[1][2] += a1 * b2; acc[1][3] += a1 * b3;
      acc[2][0] += a2 * b0; acc[2][1] += a2 * b1; acc[2][2] += a2 * b2; acc[2][3] += a2 * b3;
      acc[3][0] += a3 * b0; acc[3][1] += a3 * b1; acc[3][2] += a3 * b2; acc[3][3] += a3 * b3;
    }
  }
  const int col = bn * 64 + tx * 4;
  float4 bv = make_float4(0.f, 0.f, 0.f, 0.f);
  if (bias) bv = *(const float4*)(bias + col);
#pragma unroll
  for (int i = 0; i < 4; ++i) {
    size_t row = (size_t)bm * 64 + ty * 4 + i;
    float4 v = make_float4(acc[i][0] + bv.x, acc[i][1] + bv.y,
                           acc[i][2] + bv.z, acc[i][3] + bv.w);
    *(float4*)(C + row * N + col) = v;
  }
}

// ------------- rowdot: out[n] = dot(x[n, 0:K], w[0:K]) ----------------------
__global__ __launch_bounds__(256) void rowdot_kernel(const float* __restrict__ x,
    const float* __restrict__ w, float* __restrict__ out, int N, int K) {
  int row = blockIdx.x * 4 + (threadIdx.x >> 6);
  if (row >= N) return;
  int lane = threadIdx.x & 63;
  const float* xp = x + (size_t)row * K;
  float p = 0.f;
  for (int k = lane; k < K; k += 64) p += xp[k] * w[k];
  for (int off = 32; off; off >>= 1) p += __shfl_down(p, off);
  if (lane == 0) out[row] = p;
}

// ----------------------- CSR build ------------------------------------------
__global__ __launch_bounds__(256) void deg_kernel(const int* __restrict__ dst,
    int* __restrict__ deg, int E) {
  int e = blockIdx.x * 256 + threadIdx.x;
  if (e < E) atomicAdd(deg + dst[e], 1);
}

__global__ __launch_bounds__(256) void scan1_kernel(const int* __restrict__ deg,
    int* __restrict__ bsum, int n) {
  __shared__ int sh[4];
  int b = blockIdx.x, tid = threadIdx.x;
  int lane = tid & 63, wid = tid >> 6;
  int v = 0;
#pragma unroll
  for (int j = 0; j < 4; ++j) {
    int i = b * 1024 + j * 256 + tid;
    if (i < n) v += deg[i];
  }
  for (int off = 32; off; off >>= 1) v += __shfl_down(v, off);
  if (lane == 0) sh[wid] = v;
  __syncthreads();
  if (tid == 0) bsum[b] = sh[0] + sh[1] + sh[2] + sh[3];
}

__global__ __launch_bounds__(64) void scan2_kernel(int* __restrict__ bsum, int nb,
    int* __restrict__ rp_end) {
  int tid = threadIdx.x;
  int v = (tid < nb) ? bsum[tid] : 0;
  int x = v;
#pragma unroll
  for (int off = 1; off < 64; off <<= 1) {
    int y = __shfl_up(x, off);
    if (tid >= off) x += y;
  }
  if (tid < nb) bsum[tid] = x - v;
  if (tid == 63) *rp_end = x;
}

__global__ __launch_bounds__(256) void scan3_kernel(const int* __restrict__ deg,
    const int* __restrict__ bsum, int* __restrict__ rp, int n) {
  __shared__ int wsum[4];
  int b = blockIdx.x, tid = threadIdx.x;
  int lane = tid & 63, wid = tid >> 6;
  int carry = bsum[b];
#pragma unroll
  for (int c = 0; c < 4; ++c) {
    int i = b * 1024 + c * 256 + tid;
    int v = (i < n) ? deg[i] : 0;
    int x = v;
#pragma unroll
    for (int off = 1; off < 64; off <<= 1) {
      int y = __shfl_up(x, off);
      if (lane >= off) x += y;
    }
    if (lane == 63) wsum[wid] = x;
    __syncthreads();
    int woff = 0;
    for (int k = 0; k < wid; ++k) woff += wsum[k];
    if (i < n) rp[i] = carry + woff + x - v;
    carry += wsum[0] + wsum[1] + wsum[2] + wsum[3];
    __syncthreads();
  }
}

__global__ __launch_bounds__(256) void copy_kernel(const int* __restrict__ a,
    int* __restrict__ b, int n) {
  int i = blockIdx.x * 256 + threadIdx.x;
  if (i < n) b[i] = a[i];
}

__global__ __launch_bounds__(256) void fill_kernel(const int* __restrict__ dst,
    int* __restrict__ cursor, int* __restrict__ eidx, int E) {
  int e = blockIdx.x * 256 + threadIdx.x;
  if (e >= E) return;
  int pos = atomicAdd(cursor + dst[e], 1);
  eidx[pos] = e;
}

// ---- edge accumulation helper (shfl-batched CSR walk, bf16 messages) -------
__device__ inline void acc_edges(const unsigned short* __restrict__ h,
    const int* __restrict__ rp, const int* __restrict__ eidx,
    const int* __restrict__ esrc, const float* __restrict__ ew,
    int d, int lane, float4& a0, float4& a1) {
  int beg = rp[d], end = rp[d + 1];
  for (int base = beg; base < end; base += 64) {
    int cnt = end - base; if (cnt > 64) cnt = 64;
    int s = 0; float w = 0.f;
    if (lane < cnt) {
      int e = eidx[base + lane];
      s = esrc[e];
      w = ew[e];
    }
    for (int j = 0; j < cnt; ++j) {
      int sj = __shfl(s, j);
      float wj = __shfl(w, j);
      ushort8 hv = *(const ushort8*)(h + (size_t)sj * HD + lane * 8);
      a0.x += wj * bf2f(hv[0]); a0.y += wj * bf2f(hv[1]);
      a0.z += wj * bf2f(hv[2]); a0.w += wj * bf2f(hv[3]);
      a1.x += wj * bf2f(hv[4]); a1.y += wj * bf2f(hv[5]);
      a1.z += wj * bf2f(hv[6]); a1.w += wj * bf2f(hv[7]);
    }
  }
}

// ---- merged gather: audio nodes (aa edges + va edges, fused) then video ----
// one wave per dst node; 8 ch/lane. Q written ONCE (no aa->va round trip).
__global__ __launch_bounds__(256) void gather_all(
    const unsigned short* __restrict__ S_a, const unsigned short* __restrict__ S_s,
    const unsigned short* __restrict__ S_v,
    const int* __restrict__ rp_aa, const int* __restrict__ ex_aa, const int* __restrict__ ei_aa,
    const float* __restrict__ ew_aa,
    const int* __restrict__ rp_va, const int* __restrict__ ex_va, const int* __restrict__ ei_va,
    const float* __restrict__ elog,
    const int* __restrict__ rp_vv, const int* __restrict__ ex_vv, const int* __restrict__ ei_vv,
    const float* __restrict__ ew_vv,
    const float* __restrict__ b_aa, const float* __restrict__ b_gat,
    const float* __restrict__ b_vv,
    float* __restrict__ Q, float* __restrict__ P) {
  int idx = blockIdx.x * 4 + (threadIdx.x >> 6);
  int lane = threadIdx.x & 63;
  float4 a0, a1;
  if (idx < NA) {
    // audio: init b_aa + b_gat, then aa-GCN edges, then va-GAT edges
    a0 = *(const float4*)(b_aa + lane * 8);
    a1 = *(const float4*)(b_aa + lane * 8 + 4);
    float4 c0 = *(const float4*)(b_gat + lane * 8);
    float4 c1 = *(const float4*)(b_gat + lane * 8 + 4);
    a0.x += c0.x; a0.y += c0.y; a0.z += c0.z; a0.w += c0.w;
    a1.x += c1.x; a1.y += c1.y; a1.z += c1.z; a1.w += c1.w;
    acc_edges(S_a, rp_aa, ex_aa, ei_aa, ew_aa, idx, lane, a0, a1);
    acc_edges(S_s, rp_va, ex_va, ei_va, elog, idx, lane, a0, a1);
    float* op = Q + (size_t)idx * HD + lane * 8;
    *(float4*)(op) = a0;
    *(float4*)(op + 4) = a1;
  } else {
    int d = idx - NA;   // video node (grid sized so d < NV)
    a0 = *(const float4*)(b_vv + lane * 8);
    a1 = *(const float4*)(b_vv + lane * 8 + 4);
    acc_edges(S_v, rp_vv, ex_vv, ei_vv, ew_vv, d, lane, a0, a1);
    float* op = P + (size_t)d * HD + lane * 8;
    *(float4*)(op) = a0;
    *(float4*)(op + 4) = a1;
  }
}

// ------------------------- GAT helpers --------------------------------------
__device__ inline unsigned enc_f(float f) {
  unsigned u = __float_as_uint(f);
  return (u & 0x80000000u) ? ~u : (u | 0x80000000u);
}
__device__ inline float dec_f(unsigned k) {
  unsigned u = (k & 0x80000000u) ? (k ^ 0x80000000u) : ~k;
  return __uint_as_float(u);
}

__global__ __launch_bounds__(256) void gat_init_kernel(unsigned* __restrict__ segmax,
    float* __restrict__ segsum, int N) {
  int i = blockIdx.x * 256 + threadIdx.x;
  if (i < N) { segmax[i] = 0x007FFFFFu; segsum[i] = 0.f; }
}

__global__ __launch_bounds__(256) void gat_p1_kernel(const float* __restrict__ hs_dot,
    const float* __restrict__ hd_dot, const int* __restrict__ ei,
    unsigned* __restrict__ segmax, int E) {
  int e = blockIdx.x * 256 + threadIdx.x;
  if (e >= E) return;
  int s = ei[e], d = ei[E + e];
  float l = hs_dot[s] + hd_dot[d];
  l = (l > 0.f) ? l : 0.2f * l;
  atomicMax(segmax + d, enc_f(l));
}

__global__ __launch_bounds__(256) void gat_p2_kernel(const float* __restrict__ hs_dot,
    const float* __restrict__ hd_dot, const int* __restrict__ ei,
    const unsigned* __restrict__ segmax, float* __restrict__ segsum,
    float* __restrict__ elog, int E) {
  int e = blockIdx.x * 256 + threadIdx.x;
  if (e >= E) return;
  int s = ei[e], d = ei[E + e];
  float l = hs_dot[s] + hd_dot[d];
  l = (l > 0.f) ? l : 0.2f * l;
  float m = dec_f(segmax[d]);
  float ex = __expf(l - m);
  elog[e] = ex;
  atomicAdd(segsum + d, ex);
}

__global__ __launch_bounds__(256) void gat_p2b_kernel(const int* __restrict__ ei,
    const float* __restrict__ segsum, float* __restrict__ elog, int E) {
  int e = blockIdx.x * 256 + threadIdx.x;
  if (e >= E) return;
  int d = ei[E + e];
  elog[e] = elog[e] / segsum[d];
}

// ------ merged graph norm: blocks [0,NB) audio (100 rows), [NB,2NB) video ---
__device__ inline void norm_body(const float* __restrict__ src,
    float* __restrict__ dst, const float* __restrict__ w,
    const float* __restrict__ b, int g, int rows) {
  int tid = threadIdx.x;
  const size_t base = (size_t)g * rows * HD;
  double s = 0.0, s2 = 0.0;
  for (int n = 0; n < rows; ++n) {
    float v = fmaxf(src[base + (size_t)n * HD + tid], 0.f);
    s += v; s2 += (double)v * v;
  }
  for (int off = 32; off; off >>= 1) { s += __shfl_down(s, off); s2 += __shfl_down(s2, off); }
  __shared__ double rs[8], rs2[8];
  int lane = tid & 63, wid = tid >> 6;
  if (lane == 0) { rs[wid] = s; rs2[wid] = s2; }
  __syncthreads();
  __shared__ float mean_s, rstd_s;
  if (tid == 0) {
    double S = 0, S2 = 0;
    for (int i = 0; i < 8; ++i) { S += rs[i]; S2 += rs2[i]; }
    double M = (double)rows * (double)HD;
    double mean = S / M;
    double var = S2 / M - mean * mean;
    mean_s = (float)mean;
    rstd_s = (float)(1.0 / sqrt(var + 1e-5));
  }
  __syncthreads();
  float mean = mean_s, rstd = rstd_s;
  float ww = w[tid], bb = b[tid];
  for (int n = 0; n < rows; ++n) {
    float v = fmaxf(src[base + (size_t)n * HD + tid], 0.f);
    dst[base + (size_t)n * HD + tid] = ww * (v - mean) * rstd + bb;
  }
}

__global__ __launch_bounds__(512) void norm2_kernel(float* __restrict__ Q,
    const float* __restrict__ wa, const float* __restrict__ ba,
    float* __restrict__ P, const float* __restrict__ wv,
    const float* __restrict__ bv) {
  int g = blockIdx.x;
  if (g < NB) norm_body(Q, Q, wa, ba, g, 100);
  else        norm_body(P, P, wv, bv, g - NB, 40);
}

// ------------- readout: global attention over 100 audio nodes per graph -----
__global__ __launch_bounds__(512) void readout_kernel(const float* __restrict__ xa,
    const float* __restrict__ att_w, float* __restrict__ ge) {
  int g = blockIdx.x;
  int tid = threadIdx.x;
  int lane = tid & 63, wid = tid >> 6;
  const float* xg = xa + (size_t)g * 100 * HD;
  __shared__ float gv[112];
  for (int n = wid; n < 100; n += 8) {
    float p = 0.f;
#pragma unroll
    for (int j = 0; j < 8; ++j) p += xg[(size_t)n * HD + j * 64 + lane] * att_w[j * 64 + lane];
    for (int off = 32; off; off >>= 1) p += __shfl_down(p, off);
    if (lane == 0) gv[n] = p;
  }
  __syncthreads();
  __shared__ float inv_s;
  if (tid == 0) {
    float m = -1e30f;
    for (int n = 0; n < 100; ++n) m = fmaxf(m, gv[n]);
    float ssum = 0.f;
    for (int n = 0; n < 100; ++n) { float e = __expf(gv[n] - m); gv[n] = e; ssum += e; }
    inv_s = 1.0f / fmaxf(ssum, 1e-16f);
  }
  __syncthreads();
  float inv = inv_s;
  float acc = 0.f;
  for (int n = 0; n < 100; ++n) acc += gv[n] * xg[(size_t)n * HD + tid];
  ge[(size_t)g * HD + tid] = acc * inv;
}

// ----------------------------------------------------------------------------
extern "C" void kernel_launch(void* const* d_in, const int* in_sizes, int n_in,
                              void* d_out, int out_size, void* d_ws, size_t ws_size,
                              hipStream_t stream) {
  const float* x_video = (const float*)d_in[0];
  const float* x_audio = (const float*)d_in[1];
  const float* ew_vv   = (const float*)d_in[2];
  const float* ew_aa   = (const float*)d_in[3];
  const float* W_vv0   = (const float*)d_in[4];
  const float* W_aa0   = (const float*)d_in[5];
  const float* W_src0  = (const float*)d_in[6];
  const float* W_dst0  = (const float*)d_in[7];
  const float* W_vv    = (const float*)d_in[8];
  const float* W_aa    = (const float*)d_in[9];
  const float* W_src   = (const float*)d_in[10];
  const float* W_dst   = (const float*)d_in[11];
  const float* b_vv    = (const float*)d_in[12];
  const float* b_aa    = (const float*)d_in[13];
  const float* b_gat   = (const float*)d_in[14];
  const float* a_src   = (const float*)d_in[15];
  const float* a_dst   = (const float*)d_in[16];
  const float* ln_v_w  = (const float*)d_in[17];
  const float* ln_v_b  = (const float*)d_in[18];
  const float* ln_a_w  = (const float*)d_in[19];
  const float* ln_a_b  = (const float*)d_in[20];
  const float* att_w   = (const float*)d_in[21];
  const float* lin_W   = (const float*)d_in[22];
  const float* lin_b   = (const float*)d_in[23];
  const int*   ei_vv   = (const int*)d_in[24];
  const int*   ei_aa   = (const int*)d_in[25];
  const int*   ei_va   = (const int*)d_in[26];

  // ---- workspace carve-up (4B units); ~242 MB (same as round 8) ----
  const size_t WT_ELEMS = (size_t)HD * DV;
  const size_t REQ = (size_t)NV * HD + (size_t)NA * HD
                   + (size_t)NA * HD / 2 + (size_t)NV * HD   // S_a + S_s + S_v
                   + NV + NA + 1024 + 512 + NA + NA + EVA + (size_t)NB * HD
                   + (NV + 1) + EVV + (NA + 1) + EAA + (NA + 1) + EVA
                   + 3 * (WT_ELEMS / 2) + 64;
  if (ws_size < REQ * sizeof(float)) return;

  float* p = (float*)d_ws;
  float* P  = p; p += (size_t)NV * HD;
  float* Q  = p; p += (size_t)NA * HD;
  unsigned short* S_a = (unsigned short*)p; p += (size_t)NA * HD / 2;  // ha bf16
  unsigned short* S_s = (unsigned short*)p; p += (size_t)NV * HD / 2;  // hs bf16
  unsigned short* S_v = (unsigned short*)p; p += (size_t)NV * HD / 2;  // hv bf16
  float* hs_dot = p; p += NV;
  float* hd_dot = p; p += NA;
  float* wsa    = p; p += 1024;
  float* wda    = p; p += 512;
  unsigned* segmax = (unsigned*)p; p += NA;
  float* segsum = p; p += NA;
  float* elog   = p; p += EVA;
  float* ge     = p; p += (size_t)NB * HD;
  int* rp_vv = (int*)p; p += NV + 1;
  int* ex_vv = (int*)p; p += EVV;
  int* rp_aa = (int*)p; p += NA + 1;
  int* ex_aa = (int*)p; p += EAA;
  int* rp_va = (int*)p; p += NA + 1;
  int* ex_va = (int*)p; p += EVA;
  unsigned short* Wt_v = (unsigned short*)p; p += WT_ELEMS / 2;
  unsigned short* Wt_a = (unsigned short*)p; p += WT_ELEMS / 2;
  unsigned short* Wt_s = (unsigned short*)p; p += WT_ELEMS / 2;
  int* bsum = (int*)p; p += 64;

  int* degbuf = (int*)segmax;
  int* curbuf = (int*)segsum;

  // ---- build CSR (once; edge lists shared by all 4 layers) ----
  {
    struct { const int* dst; int* rp; int* ex; int N; int E; } g[3] = {
      { ei_vv + EVV, rp_vv, ex_vv, NV, EVV },
      { ei_aa + EAA, rp_aa, ex_aa, NA, EAA },
      { ei_va + EVA, rp_va, ex_va, NA, EVA },
    };
    for (int i = 0; i < 3; ++i) {
      int nb = (g[i].N + 1023) / 1024;
      hipMemsetAsync(degbuf, 0, (size_t)g[i].N * sizeof(int), stream);
      deg_kernel<<<(g[i].E + 255) / 256, 256, 0, stream>>>(g[i].dst, degbuf, g[i].E);
      scan1_kernel<<<nb, 256, 0, stream>>>(degbuf, bsum, g[i].N);
      scan2_kernel<<<1, 64, 0, stream>>>(bsum, nb, g[i].rp + g[i].N);
      scan3_kernel<<<nb, 256, 0, stream>>>(degbuf, bsum, g[i].rp, g[i].N);
      copy_kernel<<<(g[i].N + 255) / 256, 256, 0, stream>>>(g[i].rp, curbuf, g[i].N);
      fill_kernel<<<(g[i].E + 255) / 256, 256, 0, stream>>>(g[i].dst, curbuf, g[i].ex, g[i].E);
    }
  }

  const float* xv_cur = x_video;
  const float* xa_cur = x_audio;

  for (int i = 0; i < NL; ++i) {
    const int Kv = (i == 0) ? DV : HD;
    const int Ka = (i == 0) ? DA : HD;
    const float* Wv = (i == 0) ? W_vv0  : W_vv  + (size_t)(i - 1) * HD * HD;
    const float* Wa = (i == 0) ? W_aa0  : W_aa  + (size_t)(i - 1) * HD * HD;
    const float* Ws = (i == 0) ? W_src0 : W_src + (size_t)(i - 1) * HD * HD;
    const float* Wd = (i == 0) ? W_dst0 : W_dst + (size_t)(i - 1) * HD * HD;

    // ---- transpose-cast weights to bf16 [512 x K] ----
    tcast_kernel<<<dim3(HD / 32, Kv / 32), 256, 0, stream>>>(Wv, Wt_v, Kv);
    tcast_kernel<<<dim3(HD / 32, Ka / 32), 256, 0, stream>>>(Wa, Wt_a, Ka);
    tcast_kernel<<<dim3(HD / 32, Kv / 32), 256, 0, stream>>>(Ws, Wt_s, Kv);

    // ---- attention logit dots ((x@W)@a == x@(W@a)) ----
    rowdot_kernel<<<(Ka + 3) / 4, 256, 0, stream>>>(Wd, a_dst + i * HD, wda, Ka, HD);
    rowdot_kernel<<<NA / 4, 256, 0, stream>>>(xa_cur, wda, hd_dot, NA, Ka);
    rowdot_kernel<<<(Kv + 3) / 4, 256, 0, stream>>>(Ws, a_src + i * HD, wsa, Kv, HD);
    rowdot_kernel<<<NV / 4, 256, 0, stream>>>(xv_cur, wsa, hs_dot, NV, Kv);

    // ---- GAT softmax over incoming va edges ----
    gat_init_kernel<<<(NA + 255) / 256, 256, 0, stream>>>(segmax, segsum, NA);
    gat_p1_kernel<<<(EVA + 255) / 256, 256, 0, stream>>>(hs_dot, hd_dot, ei_va, segmax, EVA);
    gat_p2_kernel<<<(EVA + 255) / 256, 256, 0, stream>>>(hs_dot, hd_dot, ei_va, segmax, segsum, elog, EVA);
    gat_p2b_kernel<<<(EVA + 255) / 256, 256, 0, stream>>>(ei_va, segsum, elog, EVA);

    // ---- ALL three GEMMs in one grid (TLP; XCD-swizzled A-reuse) ----
    mfma_gemm3<<<GTOT, 256, 0, stream>>>(xv_cur, xa_cur, Wt_s, Wt_v, Wt_a,
                                         S_s, S_v, S_a, Kv, Ka);

    // ---- ALL gathers in one grid; audio fuses aa + va (Q written once) ----
    gather_all<<<(NA + NV) / 4, 256, 0, stream>>>(S_a, S_s, S_v,
        rp_aa, ex_aa, ei_aa, ew_aa, rp_va, ex_va, ei_va, elog,
        rp_vv, ex_vv, ei_vv, ew_vv,
        b_aa + i * HD, b_gat + i * HD, b_vv + i * HD, Q, P);

    // ---- relu + graph norm, both node types in one grid (in place) ----
    norm2_kernel<<<NB * 2, 512, 0, stream>>>(Q, ln_a_w + i * HD, ln_a_b + i * HD,
                                             P, ln_v_w + i * HD, ln_v_b + i * HD);

    xv_cur = P;
    xa_cur = Q;
  }

  // ---- readout + final linear (small, stays fp32) ----
  readout_kernel<<<NB, 512, 0, stream>>>(Q, att_w, ge);
  gemm64<<<dim3(NOUT / 64, NB / 64), 256, 0, stream>>>(ge, lin_W, lin_b, (float*)d_out, NB, NOUT, HD);
}